// Round 1
// baseline (113.555 us; speedup 1.0000x reference)
//
#include <hip/hip_runtime.h>
#include <math.h>

#define BB 64
#define LL 8192
#define DD 64
#define NC 16
#define CHUNK (LL / NC) // 512

// ---------------- K1: collect stage (logits + partial softmax + partial PV) --
// grid = BB*NC blocks, 512 threads (8 waves).
// Each block handles one (b, chunk of 512 positions).
__global__ __launch_bounds__(512) void k_collect(
    const float* __restrict__ q, const float* __restrict__ kc,
    const float* __restrict__ v, const float* __restrict__ tc_p,
    float* __restrict__ out_logits, float* __restrict__ mws,
    float* __restrict__ sws, float* __restrict__ pvws)
{
    __shared__ float qs[DD];
    __shared__ float ps[CHUNK];
    __shared__ float red[32 * DD];
    __shared__ float wred[8];

    const int tid = threadIdx.x;
    const int b = blockIdx.x / NC;
    const int c = blockIdx.x % NC;
    const int l0 = c * CHUNK;

    if (tid < DD) qs[tid] = q[b * DD + tid];
    __syncthreads();

    const float inv_tc = 1.0f / tc_p[0];
    const int j = tid & 15;   // lane within 16-lane group
    const int g = tid >> 4;   // group id 0..31

    const float4 q4 = *(const float4*)&qs[j * 4];

    const float* kcb = kc + ((size_t)b * LL + l0) * DD;

    // Phase A: logits. Each 16-lane group computes one dot per iteration.
    // Wave = 4 groups -> 4 consecutive rows x 256B = 1KB contiguous load.
    float lmax = -INFINITY;
    #pragma unroll
    for (int it = 0; it < 16; ++it) {
        const int l = it * 32 + g;
        const float4 k4 = *(const float4*)&kcb[(size_t)l * DD + j * 4];
        float d = k4.x * q4.x + k4.y * q4.y + k4.z * q4.z + k4.w * q4.w;
        d += __shfl_xor(d, 1);
        d += __shfl_xor(d, 2);
        d += __shfl_xor(d, 4);
        d += __shfl_xor(d, 8);
        const float logit = d * inv_tc;
        if (j == 0) {
            ps[l] = logit;
            out_logits[(size_t)b * LL + l0 + l] = logit;
        }
        lmax = fmaxf(lmax, logit);
    }
    // wave max (4 groups -> 64 lanes)
    lmax = fmaxf(lmax, __shfl_xor(lmax, 16));
    lmax = fmaxf(lmax, __shfl_xor(lmax, 32));
    if ((tid & 63) == 0) wred[tid >> 6] = lmax;
    __syncthreads(); // (A) ps + wred visible

    float m = wred[0];
    #pragma unroll
    for (int w = 1; w < 8; ++w) m = fmaxf(m, wred[w]);

    const float e = __expf(ps[tid] - m);
    __syncthreads(); // (B) everyone done reading wred/ps

    ps[tid] = e;
    float lsum = e;
    lsum += __shfl_xor(lsum, 1);
    lsum += __shfl_xor(lsum, 2);
    lsum += __shfl_xor(lsum, 4);
    lsum += __shfl_xor(lsum, 8);
    lsum += __shfl_xor(lsum, 16);
    lsum += __shfl_xor(lsum, 32);
    if ((tid & 63) == 0) wred[tid >> 6] = lsum;
    __syncthreads(); // (C) exp values + partial sums visible

    float s = wred[0];
    #pragma unroll
    for (int w = 1; w < 8; ++w) s += wred[w];

    // Phase B: partial PV. Thread (g=row, j=dim quad): coalesced float4 on v.
    const int d4 = j * 4;
    const int lr = g;
    const float* vb = v + ((size_t)b * LL + l0) * DD;
    float4 acc = make_float4(0.f, 0.f, 0.f, 0.f);
    #pragma unroll
    for (int i = 0; i < 16; ++i) {
        const int l = i * 32 + lr;
        const float p = ps[l];
        const float4 v4 = *(const float4*)&vb[(size_t)l * DD + d4];
        acc.x += p * v4.x;
        acc.y += p * v4.y;
        acc.z += p * v4.z;
        acc.w += p * v4.w;
    }
    *(float4*)&red[lr * DD + d4] = acc;
    __syncthreads();

    if (tid < DD) {
        float sum = 0.f;
        #pragma unroll
        for (int r = 0; r < 32; ++r) sum += red[r * DD + tid];
        pvws[((size_t)b * NC + c) * DD + tid] = sum;
    }
    if (tid == 0) {
        mws[b * NC + c] = m;
        sws[b * NC + c] = s;
    }
}

// ---------------- K2: combine chunk partials -> attn[b][d] ------------------
__global__ __launch_bounds__(64) void k_reduce(
    const float* __restrict__ mws, const float* __restrict__ sws,
    const float* __restrict__ pvws, float* __restrict__ attn_ws)
{
    const int b = blockIdx.x;
    const int d = threadIdx.x;
    float M = -INFINITY;
    #pragma unroll
    for (int c = 0; c < NC; ++c) M = fmaxf(M, mws[b * NC + c]);
    float S = 0.f, a = 0.f;
    #pragma unroll
    for (int c = 0; c < NC; ++c) {
        const float w = __expf(mws[b * NC + c] - M);
        S += w * sws[b * NC + c];
        a += w * pvws[((size_t)b * NC + c) * DD + d];
    }
    attn_ws[b * DD + d] = a / S;
}

// ---------------- K3: diffuse stage (gate * attn broadcast) -----------------
// grid = BB * LL/64 blocks, 256 threads. 64 positions per block.
__global__ __launch_bounds__(256) void k_diffuse(
    const float* __restrict__ q, const float* __restrict__ kd,
    const float* __restrict__ td_p, const float* __restrict__ attn_ws,
    float* __restrict__ out)
{
    __shared__ float qs[DD];
    __shared__ float as[DD];
    const int tid = threadIdx.x;
    const int blocksPerB = LL / 64; // 128
    const int b = blockIdx.x / blocksPerB;
    const int l0 = (blockIdx.x % blocksPerB) * 64;

    if (tid < DD) {
        qs[tid] = q[b * DD + tid];
        as[tid] = attn_ws[b * DD + tid];
    }
    __syncthreads();

    const float inv_td = 1.0f / td_p[0];
    const int j = tid & 15;  // dim quad
    const int g = tid >> 4;  // position group 0..15

    const float4 q4 = *(const float4*)&qs[j * 4];
    const float4 a4 = *(const float4*)&as[j * 4];

    const float* kdb = kd + ((size_t)b * LL + l0) * DD;
    float* ob = out + ((size_t)b * LL + l0) * DD;

    #pragma unroll
    for (int it = 0; it < 4; ++it) {
        const int l = it * 16 + g;
        const float4 k4 = *(const float4*)&kdb[(size_t)l * DD + j * 4];
        float d = k4.x * q4.x + k4.y * q4.y + k4.z * q4.z + k4.w * q4.w;
        d += __shfl_xor(d, 1);
        d += __shfl_xor(d, 2);
        d += __shfl_xor(d, 4);
        d += __shfl_xor(d, 8);
        const float gate = 1.0f / (1.0f + __expf(-d * inv_td));
        float4 o4;
        o4.x = gate * a4.x;
        o4.y = gate * a4.y;
        o4.z = gate * a4.z;
        o4.w = gate * a4.w;
        *(float4*)&ob[(size_t)l * DD + j * 4] = o4;
    }
}

extern "C" void kernel_launch(void* const* d_in, const int* in_sizes, int n_in,
                              void* d_out, int out_size, void* d_ws, size_t ws_size,
                              hipStream_t stream) {
    const float* q  = (const float*)d_in[0];
    const float* kc = (const float*)d_in[1];
    const float* kd = (const float*)d_in[2];
    const float* v  = (const float*)d_in[3];
    const float* tc = (const float*)d_in[4];
    const float* td = (const float*)d_in[5];

    float* out        = (float*)d_out;
    float* out_logits = out + (size_t)BB * LL * DD;

    // workspace layout (floats): mws[B*NC] | sws[B*NC] | pvws[B*NC*D] | attn[B*D]
    float* ws   = (float*)d_ws;
    float* mws  = ws;
    float* sws  = mws + BB * NC;
    float* pvws = sws + BB * NC;
    float* attn = pvws + (size_t)BB * NC * DD;

    k_collect<<<BB * NC, 512, 0, stream>>>(q, kc, v, tc, out_logits, mws, sws, pvws);
    k_reduce<<<BB, DD, 0, stream>>>(mws, sws, pvws, attn);
    k_diffuse<<<BB * (LL / 64), 256, 0, stream>>>(q, kd, td, attn, out);
}